// Round 1
// baseline (742.349 us; speedup 1.0000x reference)
//
#include <hip/hip_runtime.h>
#include <cstdint>
#include <cstddef>

// N=65536 samples, Din=256, Dout=768, fused K = 512 (=[h0|S])
#define NSAMP 65536
#define KDIM  512
#define MDIM  768

typedef __attribute__((ext_vector_type(8))) short bf16x8v;
typedef __attribute__((ext_vector_type(4))) float f32x4;

__device__ __forceinline__ unsigned short f2bf(float f) {
  union { float f; unsigned int u; } v; v.f = f;
  unsigned int r = v.u + 0x7fffu + ((v.u >> 16) & 1u);
  return (unsigned short)(r >> 16);
}

// ---------------- pack A = [h0 | h0+h1+h2] as bf16 [N][512] ----------------
__global__ __launch_bounds__(256) void prep_A_kernel(const float* __restrict__ x,
                                                     unsigned short* __restrict__ A) {
  int gid = blockIdx.x * 256 + threadIdx.x;   // n*64 + cg
  int n  = gid >> 6;
  int cg = gid & 63;                           // group of 4 floats, c = cg*4
  const float4* xr = (const float4*)(x + (size_t)n * 768);
  float4 a = xr[cg];
  float4 b = xr[64 + cg];
  float4 c = xr[128 + cg];
  ushort4 lo, hi;
  lo.x = f2bf(a.x); lo.y = f2bf(a.y); lo.z = f2bf(a.z); lo.w = f2bf(a.w);
  hi.x = f2bf(a.x + b.x + c.x); hi.y = f2bf(a.y + b.y + c.y);
  hi.z = f2bf(a.z + b.z + c.z); hi.w = f2bf(a.w + b.w + c.w);
  unsigned short* Arow = A + (size_t)n * KDIM;
  *(ushort4*)(Arow + cg * 4) = lo;
  *(ushort4*)(Arow + 256 + cg * 4) = hi;
}

// ------------- fuse weights: Bt[m][k] bf16, m<768, k<512 -------------------
// M1[i][m] = sum_j (w2a-0.5w1a)[i][j] * (w2b-0.5w1b)[j][m]      -> Bt[m][i]
// M2[i][m] = sum_j 0.5*(w1a[i][j]*(w2b+0.5w1b)[j][m] + w2a[i][j]*w1b[j][m]) -> Bt[m][256+i]
__global__ void prep_B_kernel(const float* __restrict__ w1a, const float* __restrict__ w2a,
                              const float* __restrict__ w1b, const float* __restrict__ w2b,
                              unsigned short* __restrict__ Bt, float* __restrict__ stats) {
  __shared__ float s1a[8 * 768];
  __shared__ float s2a[8 * 768];
  int m  = threadIdx.x;          // 0..767
  int i0 = blockIdx.x * 8;       // i block (grid = 32)
  for (int t = m; t < 8 * 768; t += 768) {
    s1a[t] = w1a[(size_t)i0 * 768 + t];
    s2a[t] = w2a[(size_t)i0 * 768 + t];
  }
  if (blockIdx.x == 0) { stats[m] = 0.f; stats[768 + m] = 0.f; }  // zero BN accumulators
  __syncthreads();
  float acc1[8], acc2[8];
#pragma unroll
  for (int ii = 0; ii < 8; ++ii) { acc1[ii] = 0.f; acc2[ii] = 0.f; }
  for (int j = 0; j < 768; ++j) {
    float b2 = w2b[(size_t)j * 768 + m];
    float b1 = w1b[(size_t)j * 768 + m];
    float F  = b2 - 0.5f * b1;
    float Gp = b2 + 0.5f * b1;
#pragma unroll
    for (int ii = 0; ii < 8; ++ii) {
      float a1 = s1a[ii * 768 + j];
      float a2 = s2a[ii * 768 + j];
      acc1[ii] += (a2 - 0.5f * a1) * F;
      acc2[ii] += 0.5f * (a1 * Gp + a2 * b1);
    }
  }
#pragma unroll
  for (int ii = 0; ii < 8; ++ii) {
    Bt[(size_t)m * KDIM + i0 + ii]       = f2bf(acc1[ii]);
    Bt[(size_t)m * KDIM + 256 + i0 + ii] = f2bf(acc2[ii]);
  }
}

// ---------------- main GEMM: out_pre = A @ B, + BN partial stats ------------
// 128x128 tile, BK=32, 256 threads = 4 waves (2x2), mfma 16x16x32 bf16.
__global__ __launch_bounds__(256) void gemm_kernel(const unsigned short* __restrict__ A,
                                                   const unsigned short* __restrict__ Bt,
                                                   float* __restrict__ out,
                                                   float* __restrict__ stats) {
  __shared__ __align__(16) unsigned short As[128 * 32];
  __shared__ __align__(16) unsigned short Bs[128 * 32];

  int bid = blockIdx.x;
  int bm  = bid % 6;             // col tile (M=768 -> 6)
  int bn  = bid / 6;             // row tile (N=65536 -> 512)
  int tid  = threadIdx.x;
  int wid  = tid >> 6;
  int lane = tid & 63;
  int quad = lane >> 4;
  int l15  = lane & 15;
  int wave_r = wid >> 1;         // 0..1
  int wave_c = wid & 1;          // 0..1

  size_t row0 = (size_t)bn * 128;
  int    col0 = bm * 128;

  f32x4 acc[4][4];
#pragma unroll
  for (int i = 0; i < 4; ++i)
#pragma unroll
    for (int j = 0; j < 4; ++j) acc[i][j] = (f32x4)(0.f);

  int chunk = lane & 3;          // 16B chunk within a 64B row
  int rsub  = lane >> 2;         // 0..15

  for (int k0 = 0; k0 < KDIM; k0 += 32) {
#pragma unroll
    for (int i = 0; i < 2; ++i) {
      int r = wid * 32 + i * 16 + rsub;                    // 0..127
      const unsigned short* gA = A  + (row0 + r) * KDIM + k0 + chunk * 8;
      const unsigned short* gB = Bt + (size_t)(col0 + r) * KDIM + k0 + chunk * 8;
      unsigned short* lA = As + (wid * 32 + i * 16) * 32;  // wave-uniform LDS base
      unsigned short* lB = Bs + (wid * 32 + i * 16) * 32;
      __builtin_amdgcn_global_load_lds(
          (const __attribute__((address_space(1))) void*)(uintptr_t)gA,
          (__attribute__((address_space(3))) void*)(uint32_t)(uintptr_t)lA, 16, 0, 0);
      __builtin_amdgcn_global_load_lds(
          (const __attribute__((address_space(1))) void*)(uintptr_t)gB,
          (__attribute__((address_space(3))) void*)(uint32_t)(uintptr_t)lB, 16, 0, 0);
    }
    __syncthreads();

    bf16x8v a[4], b[4];
#pragma unroll
    for (int rb = 0; rb < 4; ++rb)
      a[rb] = *(const bf16x8v*)&As[(wave_r * 64 + rb * 16 + l15) * 32 + quad * 8];
#pragma unroll
    for (int cb = 0; cb < 4; ++cb)
      b[cb] = *(const bf16x8v*)&Bs[(wave_c * 64 + cb * 16 + l15) * 32 + quad * 8];
#pragma unroll
    for (int rb = 0; rb < 4; ++rb)
#pragma unroll
      for (int cb = 0; cb < 4; ++cb)
        acc[rb][cb] = __builtin_amdgcn_mfma_f32_16x16x32_bf16(a[rb], b[cb], acc[rb][cb], 0, 0, 0);
    __syncthreads();
  }

  // epilogue: store fp32 out_pre + per-column partial sums for BN
#pragma unroll
  for (int cb = 0; cb < 4; ++cb) {
    int col = col0 + wave_c * 64 + cb * 16 + l15;
    float s1 = 0.f, s2 = 0.f;
#pragma unroll
    for (int rb = 0; rb < 4; ++rb) {
      size_t rg = row0 + wave_r * 64 + rb * 16 + quad * 4;
#pragma unroll
      for (int reg = 0; reg < 4; ++reg) {
        float v = acc[rb][cb][reg];
        out[(rg + reg) * MDIM + col] = v;
        s1 += v;
        s2 += v * v;
      }
    }
    s1 += __shfl_xor(s1, 16); s1 += __shfl_xor(s1, 32);
    s2 += __shfl_xor(s2, 16); s2 += __shfl_xor(s2, 32);
    if (quad == 0) {
      atomicAdd(&stats[col], s1);
      atomicAdd(&stats[768 + col], s2);
    }
  }
}

// ---------------- BN stats -> scale/shift ----------------------------------
__global__ void finalize_stats(const float* __restrict__ stats, const float* __restrict__ gamma,
                               const float* __restrict__ beta, float* __restrict__ ss) {
  int c = threadIdx.x;
  if (c < 768) {
    const float inv_n = 1.0f / 65536.0f;
    float mean = stats[c] * inv_n;
    float ex2  = stats[768 + c] * inv_n;
    float var  = ex2 - mean * mean;
    float scale = gamma[c] * rsqrtf(var + 1e-5f);
    ss[c]       = scale;
    ss[768 + c] = beta[c] - mean * scale;
  }
}

// ---------------- BN apply + sigmoid, in place ------------------------------
__global__ __launch_bounds__(256) void bn_sigmoid(float* __restrict__ out,
                                                  const float* __restrict__ ss) {
  int idx = blockIdx.x * 256 + threadIdx.x;  // float4 index
  int cg  = (idx % 192) * 4;                 // column group
  float4 v  = ((const float4*)out)[idx];
  float4 sc = *(const float4*)&ss[cg];
  float4 sh = *(const float4*)&ss[768 + cg];
  v.x = 1.f / (1.f + __expf(-(v.x * sc.x + sh.x)));
  v.y = 1.f / (1.f + __expf(-(v.y * sc.y + sh.y)));
  v.z = 1.f / (1.f + __expf(-(v.z * sc.z + sh.z)));
  v.w = 1.f / (1.f + __expf(-(v.w * sc.w + sh.w)));
  ((float4*)out)[idx] = v;
}

extern "C" void kernel_launch(void* const* d_in, const int* in_sizes, int n_in,
                              void* d_out, int out_size, void* d_ws, size_t ws_size,
                              hipStream_t stream) {
  const float* x     = (const float*)d_in[0];
  const float* w1a   = (const float*)d_in[1];
  const float* w2a   = (const float*)d_in[2];
  const float* w1b   = (const float*)d_in[3];
  const float* w2b   = (const float*)d_in[4];
  const float* gamma = (const float*)d_in[5];
  const float* beta  = (const float*)d_in[6];
  float* out = (float*)d_out;

  // workspace layout
  unsigned short* A  = (unsigned short*)d_ws;                                  // 64 MiB
  unsigned short* Bt = (unsigned short*)((char*)d_ws + (size_t)NSAMP * KDIM * 2);
  float* stats = (float*)((char*)Bt + (size_t)MDIM * KDIM * 2);                // 2*768 f32
  float* ss    = stats + 1536;                                                 // 2*768 f32

  prep_A_kernel<<<NSAMP * 64 / 256, 256, 0, stream>>>(x, A);
  prep_B_kernel<<<32, 768, 0, stream>>>(w1a, w2a, w1b, w2b, Bt, stats);
  gemm_kernel<<<(NSAMP / 128) * (MDIM / 128), 256, 0, stream>>>(A, Bt, out, stats);
  finalize_stats<<<1, 768, 0, stream>>>(stats, gamma, beta, ss);
  bn_sigmoid<<<(size_t)NSAMP * MDIM / 4 / 256, 256, 0, stream>>>(out, ss);
}

// Round 2
// 587.131 us; speedup vs baseline: 1.2644x; 1.2644x over previous
//
#include <hip/hip_runtime.h>
#include <cstdint>
#include <cstddef>

// N=65536 samples, Din=256, Dout=768, fused K = 512 (=[h0|S])
#define NSAMP 65536
#define KDIM  512
#define MDIM  768

typedef __attribute__((ext_vector_type(8))) _Float16 f16x8;
typedef __attribute__((ext_vector_type(4))) float f32x4;

union H2U { _Float16 h; unsigned short u; };
__device__ __forceinline__ unsigned short f2h(float f) {
  H2U v; v.h = (_Float16)f; return v.u;
}
__device__ __forceinline__ float h2f(unsigned short u) {
  H2U v; v.u = u; return (float)v.h;
}

// ---------------- pack A = [h0 | h0+h1+h2] as f16 [N][512] ----------------
__global__ __launch_bounds__(256) void prep_A_kernel(const float* __restrict__ x,
                                                     unsigned short* __restrict__ A) {
  int gid = blockIdx.x * 256 + threadIdx.x;   // n*64 + cg
  int n  = gid >> 6;
  int cg = gid & 63;                           // group of 4 floats, c = cg*4
  const float4* xr = (const float4*)(x + (size_t)n * 768);
  float4 a = xr[cg];
  float4 b = xr[64 + cg];
  float4 c = xr[128 + cg];
  ushort4 lo, hi;
  lo.x = f2h(a.x); lo.y = f2h(a.y); lo.z = f2h(a.z); lo.w = f2h(a.w);
  hi.x = f2h(a.x + b.x + c.x); hi.y = f2h(a.y + b.y + c.y);
  hi.z = f2h(a.z + b.z + c.z); hi.w = f2h(a.w + b.w + c.w);
  unsigned short* Arow = A + (size_t)n * KDIM;
  *(ushort4*)(Arow + cg * 4) = lo;
  *(ushort4*)(Arow + 256 + cg * 4) = hi;
}

// ------------- fuse weights, stage 1: fp32 partials over j-chunks ----------
// M1[i][m] = sum_j (w2a-0.5w1a)[i][j] * (w2b-0.5w1b)[j][m]
// M2[i][m] = sum_j w1a[i][j]*(0.5w2b+0.25w1b)[j][m] + w2a[i][j]*(0.5w1b)[j][m]
// grid = 32 i-chunks x 3 m-chunks x 4 j-chunks = 384 blocks, 256 thr
// temp layout: [mat(2)][jc(4)][m(768)][i(256)] fp32
__global__ __launch_bounds__(256) void prep_B_partial(const float* __restrict__ w1a,
                                                      const float* __restrict__ w2a,
                                                      const float* __restrict__ w1b,
                                                      const float* __restrict__ w2b,
                                                      float* __restrict__ temp) {
  int b = blockIdx.x;
  int jc = b & 3;
  int rem = b >> 2;          // 0..95
  int mc = rem % 3;
  int ic = rem / 3;          // 0..31
  int t = threadIdx.x;
  int m = mc * 256 + t;
  int i0 = ic * 8;
  int j0 = jc * 192;
  __shared__ __align__(16) float sC[8][192];   // w2a - 0.5*w1a
  __shared__ __align__(16) float s1[8][192];   // w1a
  __shared__ __align__(16) float s2[8][192];   // w2a
  for (int idx = t; idx < 8 * 192; idx += 256) {
    int ii = idx / 192, jj = idx % 192;
    float a1 = w1a[(size_t)(i0 + ii) * 768 + j0 + jj];
    float a2 = w2a[(size_t)(i0 + ii) * 768 + j0 + jj];
    s1[ii][jj] = a1; s2[ii][jj] = a2; sC[ii][jj] = a2 - 0.5f * a1;
  }
  __syncthreads();
  float acc1[8] = {0,0,0,0,0,0,0,0};
  float acc2[8] = {0,0,0,0,0,0,0,0};
  const float* pb1 = w1b + (size_t)j0 * 768 + m;
  const float* pb2 = w2b + (size_t)j0 * 768 + m;
  for (int jb = 0; jb < 192; jb += 4) {
    float F[4], Gp[4], Hh[4];
#pragma unroll
    for (int u = 0; u < 4; ++u) {
      float b1 = pb1[(size_t)(jb + u) * 768];
      float b2 = pb2[(size_t)(jb + u) * 768];
      F[u]  = b2 - 0.5f * b1;
      Gp[u] = 0.5f * b2 + 0.25f * b1;
      Hh[u] = 0.5f * b1;
    }
#pragma unroll
    for (int ii = 0; ii < 8; ++ii) {
      f32x4 c  = *(const f32x4*)&sC[ii][jb];
      f32x4 a1 = *(const f32x4*)&s1[ii][jb];
      f32x4 a2 = *(const f32x4*)&s2[ii][jb];
#pragma unroll
      for (int u = 0; u < 4; ++u) {
        acc1[ii] += c[u] * F[u];
        acc2[ii] += a1[u] * Gp[u] + a2[u] * Hh[u];
      }
    }
  }
  float* t1 = temp + ((size_t)jc * 768 + m) * 256 + i0;
  float* t2 = temp + ((size_t)(4 + jc) * 768 + m) * 256 + i0;
#pragma unroll
  for (int ii = 0; ii < 8; ++ii) { t1[ii] = acc1[ii]; t2[ii] = acc2[ii]; }
}

// ------------- fuse weights, stage 2: reduce j-chunks -> Bt f16 ------------
// Bt[m][i] = M1[i][m], Bt[m][256+i] = M2[i][m]. Also zero BN stats.
__global__ __launch_bounds__(256) void prep_B_convert(const float* __restrict__ temp,
                                                      unsigned short* __restrict__ Bt,
                                                      float* __restrict__ stats) {
  int idx = blockIdx.x * 256 + threadIdx.x;  // 0..196607
  int i = idx & 255;
  int m = idx >> 8;
  const float* t1 = temp + (size_t)m * 256 + i;
  const float* t2 = temp + ((size_t)4 * 768 + m) * 256 + i;
  float v1 = 0.f, v2 = 0.f;
#pragma unroll
  for (int jc = 0; jc < 4; ++jc) {
    v1 += t1[(size_t)jc * 768 * 256];
    v2 += t2[(size_t)jc * 768 * 256];
  }
  Bt[(size_t)m * KDIM + i]       = f2h(v1);
  Bt[(size_t)m * KDIM + 256 + i] = f2h(v2);
  if (idx < 1536) stats[idx] = 0.f;
}

// ---------------- main GEMM: out_pre = A @ B, + BN partial stats ------------
// 128x128 tile, BK=32, 256 threads = 4 waves (2x2), mfma 16x16x32 f16.
template <bool F16OUT>
__global__ __launch_bounds__(256) void gemm_kernel(const unsigned short* __restrict__ A,
                                                   const unsigned short* __restrict__ Bt,
                                                   float* __restrict__ outf,
                                                   unsigned short* __restrict__ outh,
                                                   float* __restrict__ stats) {
  __shared__ __align__(16) unsigned short As[128 * 32];
  __shared__ __align__(16) unsigned short Bs[128 * 32];

  int bid = blockIdx.x;
  int bm  = bid % 6;             // col tile (M=768 -> 6)
  int bn  = bid / 6;             // row tile (N=65536 -> 512)
  int tid  = threadIdx.x;
  int wid  = tid >> 6;
  int lane = tid & 63;
  int quad = lane >> 4;
  int l15  = lane & 15;
  int wave_r = wid >> 1;         // 0..1
  int wave_c = wid & 1;          // 0..1

  size_t row0 = (size_t)bn * 128;
  int    col0 = bm * 128;

  f32x4 acc[4][4];
#pragma unroll
  for (int i = 0; i < 4; ++i)
#pragma unroll
    for (int j = 0; j < 4; ++j) acc[i][j] = (f32x4)(0.f);

  int chunk = lane & 3;          // 16B chunk within a 64B row
  int rsub  = lane >> 2;         // 0..15

  for (int k0 = 0; k0 < KDIM; k0 += 32) {
#pragma unroll
    for (int i = 0; i < 2; ++i) {
      int r = wid * 32 + i * 16 + rsub;                    // 0..127
      const unsigned short* gA = A  + (row0 + r) * KDIM + k0 + chunk * 8;
      const unsigned short* gB = Bt + (size_t)(col0 + r) * KDIM + k0 + chunk * 8;
      unsigned short* lA = As + (wid * 32 + i * 16) * 32;  // wave-uniform LDS base
      unsigned short* lB = Bs + (wid * 32 + i * 16) * 32;
      __builtin_amdgcn_global_load_lds(
          (const __attribute__((address_space(1))) void*)(uintptr_t)gA,
          (__attribute__((address_space(3))) void*)(uint32_t)(uintptr_t)lA, 16, 0, 0);
      __builtin_amdgcn_global_load_lds(
          (const __attribute__((address_space(1))) void*)(uintptr_t)gB,
          (__attribute__((address_space(3))) void*)(uint32_t)(uintptr_t)lB, 16, 0, 0);
    }
    __syncthreads();

    f16x8 a[4], b[4];
#pragma unroll
    for (int rb = 0; rb < 4; ++rb)
      a[rb] = *(const f16x8*)&As[(wave_r * 64 + rb * 16 + l15) * 32 + quad * 8];
#pragma unroll
    for (int cb = 0; cb < 4; ++cb)
      b[cb] = *(const f16x8*)&Bs[(wave_c * 64 + cb * 16 + l15) * 32 + quad * 8];
#pragma unroll
    for (int rb = 0; rb < 4; ++rb)
#pragma unroll
      for (int cb = 0; cb < 4; ++cb)
        acc[rb][cb] = __builtin_amdgcn_mfma_f32_16x16x32_f16(a[rb], b[cb], acc[rb][cb], 0, 0, 0);
    __syncthreads();
  }

  // epilogue: store out_pre + per-column partial sums for BN (from fp32 accs)
#pragma unroll
  for (int cb = 0; cb < 4; ++cb) {
    int col = col0 + wave_c * 64 + cb * 16 + l15;
    float s1 = 0.f, s2 = 0.f;
#pragma unroll
    for (int rb = 0; rb < 4; ++rb) {
      size_t rg = row0 + wave_r * 64 + rb * 16 + quad * 4;
#pragma unroll
      for (int reg = 0; reg < 4; ++reg) {
        float v = acc[rb][cb][reg];
        if (F16OUT) outh[(rg + reg) * MDIM + col] = f2h(v);
        else        outf[(rg + reg) * MDIM + col] = v;
        s1 += v;
        s2 += v * v;
      }
    }
    s1 += __shfl_xor(s1, 16); s1 += __shfl_xor(s1, 32);
    s2 += __shfl_xor(s2, 16); s2 += __shfl_xor(s2, 32);
    if (quad == 0) {
      atomicAdd(&stats[col], s1);
      atomicAdd(&stats[768 + col], s2);
    }
  }
}

// ---------------- BN stats -> scale/shift ----------------------------------
__global__ void finalize_stats(const float* __restrict__ stats, const float* __restrict__ gamma,
                               const float* __restrict__ beta, float* __restrict__ ss) {
  int c = threadIdx.x;
  if (c < 768) {
    const float inv_n = 1.0f / 65536.0f;
    float mean = stats[c] * inv_n;
    float ex2  = stats[768 + c] * inv_n;
    float var  = ex2 - mean * mean;
    float scale = gamma[c] * rsqrtf(var + 1e-5f);
    ss[c]       = scale;
    ss[768 + c] = beta[c] - mean * scale;
  }
}

// ---------------- BN apply + sigmoid: f16 staging -> f32 out ---------------
__global__ __launch_bounds__(256) void bn_sigmoid_h(const unsigned short* __restrict__ outpre,
                                                    const float* __restrict__ ss,
                                                    float* __restrict__ out) {
  int idx = blockIdx.x * 256 + threadIdx.x;  // group of 8 halves
  int cg  = (idx % 96) * 8;
  f16x8 h = *(const f16x8*)(outpre + (size_t)idx * 8);
  float4 sc0 = *(const float4*)&ss[cg];
  float4 sc1 = *(const float4*)&ss[cg + 4];
  float4 sh0 = *(const float4*)&ss[768 + cg];
  float4 sh1 = *(const float4*)&ss[768 + cg + 4];
  float4 r0, r1;
  r0.x = 1.f / (1.f + __expf(-((float)h[0] * sc0.x + sh0.x)));
  r0.y = 1.f / (1.f + __expf(-((float)h[1] * sc0.y + sh0.y)));
  r0.z = 1.f / (1.f + __expf(-((float)h[2] * sc0.z + sh0.z)));
  r0.w = 1.f / (1.f + __expf(-((float)h[3] * sc0.w + sh0.w)));
  r1.x = 1.f / (1.f + __expf(-((float)h[4] * sc1.x + sh1.x)));
  r1.y = 1.f / (1.f + __expf(-((float)h[5] * sc1.y + sh1.y)));
  r1.z = 1.f / (1.f + __expf(-((float)h[6] * sc1.z + sh1.z)));
  r1.w = 1.f / (1.f + __expf(-((float)h[7] * sc1.w + sh1.w)));
  ((float4*)out)[(size_t)idx * 2]     = r0;
  ((float4*)out)[(size_t)idx * 2 + 1] = r1;
}

// ---------------- BN apply + sigmoid, in place fp32 (fallback) -------------
__global__ __launch_bounds__(256) void bn_sigmoid_f(float* __restrict__ out,
                                                    const float* __restrict__ ss) {
  int idx = blockIdx.x * 256 + threadIdx.x;  // float4 index
  int cg  = (idx % 192) * 4;
  float4 v  = ((const float4*)out)[idx];
  float4 sc = *(const float4*)&ss[cg];
  float4 sh = *(const float4*)&ss[768 + cg];
  v.x = 1.f / (1.f + __expf(-(v.x * sc.x + sh.x)));
  v.y = 1.f / (1.f + __expf(-(v.y * sc.y + sh.y)));
  v.z = 1.f / (1.f + __expf(-(v.z * sc.z + sh.z)));
  v.w = 1.f / (1.f + __expf(-(v.w * sc.w + sh.w)));
  ((float4*)out)[idx] = v;
}

extern "C" void kernel_launch(void* const* d_in, const int* in_sizes, int n_in,
                              void* d_out, int out_size, void* d_ws, size_t ws_size,
                              hipStream_t stream) {
  const float* x     = (const float*)d_in[0];
  const float* w1a   = (const float*)d_in[1];
  const float* w2a   = (const float*)d_in[2];
  const float* w1b   = (const float*)d_in[3];
  const float* w2b   = (const float*)d_in[4];
  const float* gamma = (const float*)d_in[5];
  const float* beta  = (const float*)d_in[6];
  float* out = (float*)d_out;

  // workspace layout
  size_t offA     = 0;
  size_t offBt    = offA + (size_t)NSAMP * KDIM * 2;            // 64 MiB
  size_t offTemp  = offBt + (size_t)MDIM * KDIM * 2;            // +0.75 MiB
  size_t offStats = offTemp + (size_t)2 * 4 * 768 * 256 * 4;    // +6 MiB
  size_t offSS    = offStats + 1536 * 4;
  size_t offOut   = (offSS + 1536 * 4 + 255) & ~(size_t)255;
  size_t needF16  = offOut + (size_t)NSAMP * MDIM * 2;          // ~167 MiB

  unsigned short* A    = (unsigned short*)((char*)d_ws + offA);
  unsigned short* Bt   = (unsigned short*)((char*)d_ws + offBt);
  float* temp          = (float*)((char*)d_ws + offTemp);
  float* stats         = (float*)((char*)d_ws + offStats);
  float* ss            = (float*)((char*)d_ws + offSS);
  unsigned short* oh   = (unsigned short*)((char*)d_ws + offOut);
  bool f16stage = ws_size >= needF16;

  prep_A_kernel<<<NSAMP * 64 / 256, 256, 0, stream>>>(x, A);
  prep_B_partial<<<384, 256, 0, stream>>>(w1a, w2a, w1b, w2b, temp);
  prep_B_convert<<<768, 256, 0, stream>>>(temp, Bt, stats);
  if (f16stage) {
    gemm_kernel<true><<<(NSAMP / 128) * (MDIM / 128), 256, 0, stream>>>(A, Bt, nullptr, oh, stats);
    finalize_stats<<<1, 768, 0, stream>>>(stats, gamma, beta, ss);
    bn_sigmoid_h<<<(size_t)NSAMP * MDIM / 8 / 256, 256, 0, stream>>>(oh, ss, out);
  } else {
    gemm_kernel<false><<<(NSAMP / 128) * (MDIM / 128), 256, 0, stream>>>(A, Bt, out, nullptr, stats);
    finalize_stats<<<1, 768, 0, stream>>>(stats, gamma, beta, ss);
    bn_sigmoid_f<<<(size_t)NSAMP * MDIM / 4 / 256, 256, 0, stream>>>(out, ss);
  }
}